// Round 12
// baseline (1386.928 us; speedup 1.0000x reference)
//
#include <hip/hip_runtime.h>
#include <stdint.h>

#define OUTF 11008
#define INF  4096
#define NG   32      // groups = INF/128
#define TOK  8192
#define KB4  2048    // int32 per qweight row = INF/2

// ---- main GEMM geometry: 256x256 tile, BK=64, A-in-LDS + B-direct-to-reg ----
#define BM 256
#define BN 256
#define BK 64
#define NT (INF / BK)    // 64 K-tiles
#define GX (OUTF / BN)   // 43
#define GY (TOK / BM)    // 32
#define NWG (GX * GY)    // 1376 = 8 XCD chunks x 172

typedef unsigned short u16;
typedef __attribute__((ext_vector_type(8))) short bf16x8;
typedef __attribute__((ext_vector_type(4))) float f32x4;
typedef __attribute__((ext_vector_type(16))) float f32x16;
typedef __attribute__((ext_vector_type(4))) int i32x4;

// fp32 -> bf16 round-to-nearest-even (inputs finite)
__device__ inline u16 f2bf(float f) {
  union { float f; uint32_t u; } v; v.f = f;
  return (u16)((v.u + 0x7fff + ((v.u >> 16) & 1)) >> 16);
}

// async global->LDS, 16B per lane; lds dest must be wave-uniform base (+lane*16 implicit)
__device__ inline void async_copy16(const void* g, const void* l) {
  __builtin_amdgcn_global_load_lds(
      (__attribute__((address_space(1))) void*)(g),
      (__attribute__((address_space(3))) void*)(l), 16, 0, 0);
}

#define FENCE() asm volatile("" ::: "memory")
#define BAR()   do { FENCE(); __builtin_amdgcn_s_barrier(); FENCE(); } while (0)
#define VMCNT(n) asm volatile("s_waitcnt vmcnt(" #n ")" ::: "memory")

// ---------------- fused preprocessing kernel (r8 dense version, unchanged) ----------------

#define NXU ((long long)TOK * INF / 4)    // 8,388,608
#define NWU ((long long)OUTF * KB4 / 4)   // 5,636,096
#define PREPBLK 2048

__global__ __launch_bounds__(256) void prep(const float* __restrict__ X,
                                            const int* __restrict__ QW,
                                            const float* __restrict__ scales,
                                            const float* __restrict__ zeros,
                                            u16* __restrict__ Xb,
                                            u16* __restrict__ Wb) {
  const long long stride = (long long)gridDim.x * 256;
  for (long long i = (long long)blockIdx.x * 256 + threadIdx.x; i < NXU + NWU;
       i += stride) {
    if (i < NXU) {
      const f32x4 f = __builtin_nontemporal_load((const f32x4*)X + i);
      union { u16 t[4]; uint2 v; } u;
      u.t[0] = f2bf(f[0]); u.t[1] = f2bf(f[1]);
      u.t[2] = f2bf(f[2]); u.t[3] = f2bf(f[3]);
      ((uint2*)Xb)[i] = u.v;
    } else {
      const long long j = i - NXU;          // w-unit: 4 ints of row o
      const int o = (int)(j >> 9);          // 512 units per row (2048/4)
      const int c0 = ((int)j & 511) * 4;    // int column; group = c0/64 (4 | 64)
      const int g = c0 >> 6;
      const float s = scales[o * NG + g];
      const float zs = -zeros[o * NG + g] * s;
      const i32x4 q = __builtin_nontemporal_load((const i32x4*)QW + j);
      union { u16 t[8]; int4 v; } u;
#pragma unroll
      for (int k = 0; k < 4; ++k) {
        u.t[2 * k]     = f2bf(fmaf((float)(q[k] & 15), s, zs));
        u.t[2 * k + 1] = f2bf(fmaf((float)((q[k] >> 4) & 15), s, zs));
      }
      ((int4*)Wb)[j] = u.v;                 // bf16 cols [2*c0, 2*c0+8)
    }
  }
}

// ---------------- main GEMM: A-in-LDS (proven layout) + B-direct-to-reg ----------------
// Model fix after r11: LDS BW (~110-128 B/cyc/CU) was co-equal with MFMA
// (r8: 256 KB/tile ~ 2050 cyc vs MFMA 2067 cyc -> additive, both ~50% util;
// r11's 2 blocks doubled LDS demand -> no gain). This kernel CUTS LDS bytes:
// B never touches LDS. B frags load straight from global into registers
// (redundancy only 2x: each B frag shared by the 2 wm-waves; same cache
// lines within one tile-period -> L1/L2 absorb). LDS = A only:
// 128 KB read + 32 KB stage = 160 KB/tile (~1300 cyc) << MFMA 2067.
//
// A path is r8-verbatim (zero-conflict measured): 128-B rows, granule
// xr = (r&7)^((r>>3)&3), pre-swizzled global source + linear LDS dest.
// 32x32x16 fragments (verified r7/r8): A m=lane&31, k=(lane>>5)*8+j;
// B symmetric; C/D col=lane&31, row=(reg&3)+8*(reg>>2)+4*(lane>>5).
// B global address for (t,kg,nt): row gn = bn*256+wn*64+nt*32+rr32,
// elem off = t*64 + kg*16 + hi*8  (matches A's granule k = (kg*2+hi)*8).
//
// Pipeline: breg[kg][nt] holds B(t,kg); tile t phase kg consumes it via MFMA,
// then immediately re-loads it with B(t+1,kg) (WAR resolved by program order;
// compiler inserts the vmcnt before next-tile use). Latency cover = 1 full
// tile (~4800 cyc). Manual vmcnt guards only A's global_load_lds queue.
// FIFO audit (issue order per tile: B(t+1) x8 during phases, A(t+2) x4 at
// end): end-of-tile-t outstanding = [A(t+1)4, B(t+1)8, A(t+2)4] = 16
// -> VMCNT(12) drains exactly A(t+1). Prologue [A(0)4, A(1)4, B(0)8]
// -> VMCNT(12) drains A(0). Tail t+2==NT: [A(NT-1)4, B(NT-1)8] -> VMCNT(8).
// B loads cannot cross BAR fences (asm memory clobber) -> counts robust.
// WAR on LDS: stage of slot S sits after the BAR certifying tile t's reads.

__global__ __launch_bounds__(512, 2) void gemm_bd(const u16* __restrict__ A,
                                                  const u16* __restrict__ B,
                                                  const float* __restrict__ bias,
                                                  float* __restrict__ C) {
  __shared__ __align__(16) u16 As[2][BM * BK];   // 2 x 32 KB = 64 KB total
  const int tid = threadIdx.x;
  const int lane = tid & 63;
  const int wid = __builtin_amdgcn_readfirstlane(tid >> 6);

  // XCD-local 2D grouping (r6/r8): XCD k owns bm in [4k,4k+4); 4bm x 8bn.
  const int lin = blockIdx.x;
  const int xcd = lin & 7;
  const int wgc = lin >> 3;                 // 0..171
  int bmr, bn;
  if (wgc < 160) {
    const int g = wgc >> 5, r = wgc & 31;
    bn = g * 8 + (r & 7);
    bmr = r >> 3;
  } else {
    const int r = wgc - 160;
    bn = 40 + r % 3;
    bmr = r / 3;
  }
  const int bm = xcd * 4 + bmr;

  const u16* Ab = A + (size_t)bm * BM * INF;

  // A staging (r8 verbatim): one global_load_lds covers 64 rows x 128 B;
  // pre-swizzled source granule, linear LDS dest
  const int rowoff = tid >> 3;                    // 0..63
  const int gran = (tid & 7) ^ (rowoff & 7) ^ ((rowoff >> 3) & 3);
  const u16* Asrc = Ab + (size_t)rowoff * INF + gran * 8;
  const int wid8 = wid * 8;

  // frag addressing (32x32 MFMA, r8 layout)
  const int rr32 = lane & 31;
  const int hi = lane >> 5;
  const int xr = (rr32 & 7) ^ ((rr32 >> 3) & 3);
  const int wm = wid >> 2;   // 0..1 -> 128-row half of A tile
  const int wn = wid & 3;    // 0..3 -> 64-col quarter of B tile

  // B direct-load bases: per nt, this lane's B row + hi k-offset
  const u16* Bb0 = B + (size_t)(bn * BN + wn * 64 + rr32) * INF + hi * 8;
  const u16* Bb1 = Bb0 + (size_t)32 * INF;

  f32x16 acc[4][2] = {};     // [mt 0..3][nt 0..1] -> 128 regs (unified file)
  bf16x8 breg[4][2];         // B(t, kg, nt) ring, reloaded in place

#define STAGE_A(S, TT)                                                         \
  do {                                                                         \
    async_copy16(Asrc + (size_t)0 * INF + (size_t)(TT) * BK,                   \
                 (const char*)&As[S][0] + (0 + wid8) * 128);                   \
    async_copy16(Asrc + (size_t)64 * INF + (size_t)(TT) * BK,                  \
                 (const char*)&As[S][0] + (64 + wid8) * 128);                  \
    async_copy16(Asrc + (size_t)128 * INF + (size_t)(TT) * BK,                 \
                 (const char*)&As[S][0] + (128 + wid8) * 128);                 \
    async_copy16(Asrc + (size_t)192 * INF + (size_t)(TT) * BK,                 \
                 (const char*)&As[S][0] + (192 + wid8) * 128);                 \
  } while (0)

#define LOAD_B(KG, TT)                                                         \
  do {                                                                         \
    breg[KG][0] = *(const bf16x8*)(Bb0 + (size_t)(TT) * BK + (KG) * 16);       \
    breg[KG][1] = *(const bf16x8*)(Bb1 + (size_t)(TT) * BK + (KG) * 16);       \
  } while (0)

// phase kg of tile T (A slot S): read A frags (4 ds_read_b128), 8 MFMA with
// breg[kg] = B(T,kg), then reload breg[kg] <- B(T+1,kg)
#define PH(S, T, KG)                                                           \
  do {                                                                         \
    bf16x8 af[4];                                                              \
    _Pragma("unroll") for (int mt = 0; mt < 4; ++mt)                           \
      af[mt] = *(const bf16x8*)&As[S][(wm * 128 + mt * 32 + rr32) * BK +       \
                                      ((((KG) * 2 + hi) ^ xr) * 8)];           \
    __builtin_amdgcn_s_setprio(1);                                             \
    _Pragma("unroll") for (int mt = 0; mt < 4; ++mt)                           \
      _Pragma("unroll") for (int nt = 0; nt < 2; ++nt)                         \
        acc[mt][nt] = __builtin_amdgcn_mfma_f32_32x32x16_bf16(                 \
            af[mt], breg[KG][nt], acc[mt][nt], 0, 0, 0);                       \
    __builtin_amdgcn_s_setprio(0);                                             \
    if ((T) + 1 < NT) { LOAD_B(KG, (T) + 1); }                                 \
  } while (0)

  // prologue: A(0)->slot0 (4), A(1)->slot1 (4), B(0) all 8.
  // VMCNT(12) drains the oldest 4 (= A(0)); A(1)+B(0) stay in flight.
  STAGE_A(0, 0);
  STAGE_A(1, 1);
  LOAD_B(0, 0); LOAD_B(1, 0); LOAD_B(2, 0); LOAD_B(3, 0);
  VMCNT(12);
  BAR();

  for (int t = 0; t < NT; ++t) {
    const int S = t & 1;
    PH(S, t, 0); PH(S, t, 1); PH(S, t, 2); PH(S, t, 3);
    BAR();                       // all waves done reading A slot S
    if (t + 2 < NT) {
      STAGE_A(S, t + 2);         // slot S free (certified above)
      VMCNT(12);                 // drains A(t+1); leaves B(t+1)+A(t+2)
    } else if (t + 1 < NT) {
      VMCNT(8);                  // [A(NT-1)4, B(NT-1)8] -> drain A(NT-1)
    } else {
      VMCNT(0);
    }
    BAR();                       // A(t+1) collectively visible
  }

  // epilogue: NT stores; 32x32 C/D layout col=lane&31,
  // row = (reg&3) + 8*(reg>>2) + 4*hi
  float bv[2];
#pragma unroll
  for (int nt = 0; nt < 2; ++nt)
    bv[nt] = bias[bn * BN + wn * 64 + nt * 32 + rr32];
#pragma unroll
  for (int mt = 0; mt < 4; ++mt)
#pragma unroll
    for (int nt = 0; nt < 2; ++nt) {
      const int gn = bn * BN + wn * 64 + nt * 32 + rr32;
#pragma unroll
      for (int reg = 0; reg < 16; ++reg) {
        const int gm = bm * BM + wm * 128 + mt * 32 +
                       (reg & 3) + 8 * (reg >> 2) + 4 * hi;
        __builtin_nontemporal_store(acc[mt][nt][reg] + bv[nt],
                                    &C[(size_t)gm * OUTF + gn]);
      }
    }
}

// ---------------- fused fallback (no workspace requirement) ----------------

#define FBM 128
#define FBN 128
#define FBK 64

#define FMFMA_COMPUTE()                                                       \
  do {                                                                        \
    const int frr = lane & 15;                                                \
    const int fq4 = lane >> 4;                                                \
    _Pragma("unroll") for (int ks = 0; ks < 2; ++ks) {                        \
      bf16x8 fa[4], fb[4];                                                    \
      const int kk = (((ks * 4 + fq4) ^ (frr & 7)) * 8);                      \
      _Pragma("unroll") for (int i = 0; i < 4; ++i) {                         \
        fa[i] = *(const bf16x8*)&Asf[(mwave + i * 16 + frr) * FBK + kk];      \
        fb[i] = *(const bf16x8*)&Bsf[(nwave + i * 16 + frr) * FBK + kk];      \
      }                                                                       \
      _Pragma("unroll") for (int mi = 0; mi < 4; ++mi)                        \
        _Pragma("unroll") for (int ni = 0; ni < 4; ++ni)                      \
          facc[mi][ni] = __builtin_amdgcn_mfma_f32_16x16x32_bf16(             \
              fa[mi], fb[ni], facc[mi][ni], 0, 0, 0);                         \
    }                                                                         \
  } while (0)

__global__ __launch_bounds__(256) void gemm_fused(const float* __restrict__ X,
                                                  const int* __restrict__ QW,
                                                  const float* __restrict__ scales,
                                                  const float* __restrict__ zeros,
                                                  const float* __restrict__ bias,
                                                  float* __restrict__ C) {
  __shared__ __align__(16) u16 Asf[FBM * FBK];
  __shared__ __align__(16) u16 Bsf[FBN * FBK];
  const int tid = threadIdx.x;
  const int lane = tid & 63;
  const int wid = tid >> 6;
  const int bm = blockIdx.y, bn = blockIdx.x;
  const int row = tid >> 1;
  const int half = tid & 1;
  const float* xr = X + (size_t)(bm * FBM + row) * INF + half * 32;
  const int* qr = QW + (size_t)(bn * FBN + row) * KB4 + half * 16;
  const float* srow = scales + (size_t)(bn * FBN + row) * NG;
  const float* zrow = zeros + (size_t)(bn * FBN + row) * NG;
  const int mwave = (wid >> 1) * 64;
  const int nwave = (wid & 1) * 64;
  f32x4 facc[4][4] = {};

  for (int kb = 0; kb < INF / FBK; ++kb) {
    const int k0 = kb * FBK;
    union { u16 t[32]; int4 v[4]; } ta, tb;
#pragma unroll
    for (int j = 0; j < 8; ++j) {
      const float4 f = *(const float4*)(xr + k0 + j * 4);
      ta.t[4 * j]     = f2bf(f.x);
      ta.t[4 * j + 1] = f2bf(f.y);
      ta.t[4 * j + 2] = f2bf(f.z);
      ta.t[4 * j + 3] = f2bf(f.w);
    }
    {
      const float s = srow[kb >> 1];
      const float zs = -zrow[kb >> 1] * s;
#pragma unroll
      for (int j = 0; j < 4; ++j) {
        const int4 q = *(const int4*)(qr + kb * 32 + j * 4);
        const int qq[4] = {q.x, q.y, q.z, q.w};
#pragma unroll
        for (int u = 0; u < 4; ++u) {
          tb.t[8 * j + 2 * u]     = f2bf(fmaf((float)(qq[u] & 15), s, zs));
          tb.t[8 * j + 2 * u + 1] = f2bf(fmaf((float)((qq[u] >> 4) & 15), s, zs));
        }
      }
    }
    __syncthreads();
#pragma unroll
    for (int j = 0; j < 4; ++j) {
      *(int4*)&Asf[row * FBK + (((half * 4 + j) ^ (row & 7)) * 8)] = ta.v[j];
      *(int4*)&Bsf[row * FBK + (((half * 4 + j) ^ (row & 7)) * 8)] = tb.v[j];
    }
    __syncthreads();
    FMFMA_COMPUTE();
  }
  {
    const int ncol = lane & 15;
    const int qrow = (lane >> 4) * 4;
#pragma unroll
    for (int mi = 0; mi < 4; ++mi)
#pragma unroll
      for (int ni = 0; ni < 4; ++ni) {
        const int gn = bn * FBN + nwave + ni * 16 + ncol;
        const float bvv = bias[gn];
#pragma unroll
        for (int r = 0; r < 4; ++r) {
          const int gm = bm * FBM + mwave + mi * 16 + qrow + r;
          C[(size_t)gm * OUTF + gn] = facc[mi][ni][r] + bvv;
        }
      }
  }
}

// ---------------- launch ----------------

extern "C" void kernel_launch(void* const* d_in, const int* in_sizes, int n_in,
                              void* d_out, int out_size, void* d_ws, size_t ws_size,
                              hipStream_t stream) {
  const float* x = (const float*)d_in[0];
  const int* qw = (const int*)d_in[1];
  const float* scales = (const float*)d_in[2];
  const float* zeros = (const float*)d_in[3];
  const float* bias = (const float*)d_in[4];
  float* out = (float*)d_out;

  const size_t needW = (size_t)OUTF * INF * sizeof(u16);  // 90,177,536 B
  const size_t needX = (size_t)TOK * INF * sizeof(u16);   // 67,108,864 B

  if (ws_size >= needW + needX) {
    u16* Wb = (u16*)d_ws;
    u16* Xb = (u16*)((char*)d_ws + needW);
    prep<<<PREPBLK, 256, 0, stream>>>(x, qw, scales, zeros, Xb, Wb);
    gemm_bd<<<dim3(NWG), 512, 0, stream>>>(Xb, Wb, bias, out);
  } else {
    gemm_fused<<<dim3(OUTF / FBN, TOK / FBM), 256, 0, stream>>>(x, qw, scales, zeros, bias, out);
  }
}